// Round 7
// baseline (183.021 us; speedup 1.0000x reference)
//
#include <hip/hip_runtime.h>
#include <math.h>

// DynamicElementAggregator: B=2, N=1024, M=1024, D=768, F=384, H=72
#define B_ 2
#define N_ 1024
#define M_ 1024
#define D_ 768
#define F_ 384
#define H_ 72

typedef float f32x4 __attribute__((ext_vector_type(4)));

// Raw router weights (2048 x 72, 576 KB). Fully rewritten every call.
__device__ float g_rw[B_ * N_ * H_];

// ---- K1: full router MLP: rw = GELU(x@W1 + b1) @ W2 + b2 ------------------
// (unchanged from Round 5 — known-good; isolates the combine experiment)
__global__ __launch_bounds__(384) void mlp_kernel(
    const float* __restrict__ x, const float* __restrict__ W1,
    const float* __restrict__ b1, const float* __restrict__ W2,
    const float* __restrict__ b2)
{
    const int f = threadIdx.x;            // 0..383
    const int row0 = blockIdx.x * 8;

    __shared__ float xs[8][D_];           // 24 KB
    __shared__ float hs[8][F_ + 8];       // 12.25 KB, pitch 392 (16B-aligned)

    {   // stage x rows (coalesced float4)
        const f32x4* xg = reinterpret_cast<const f32x4*>(x + row0 * D_);
        f32x4* xl = reinterpret_cast<f32x4*>(&xs[0][0]);
#pragma unroll
        for (int i = 0; i < 4; ++i)       // 1536 float4 / 384 threads
            xl[threadIdx.x + i * 384] = xg[threadIdx.x + i * 384];
    }
    __syncthreads();

    float acc[8];
#pragma unroll
    for (int r = 0; r < 8; ++r) acc[r] = 0.0f;

#pragma unroll 4
    for (int d = 0; d < D_; d += 4) {
        const float w0 = W1[(d + 0) * F_ + f];
        const float w1v = W1[(d + 1) * F_ + f];
        const float w2v = W1[(d + 2) * F_ + f];
        const float w3v = W1[(d + 3) * F_ + f];
#pragma unroll
        for (int r = 0; r < 8; ++r) {
            const float4 xv = *reinterpret_cast<const float4*>(&xs[r][d]);
            acc[r] = fmaf(xv.x, w0, acc[r]);
            acc[r] = fmaf(xv.y, w1v, acc[r]);
            acc[r] = fmaf(xv.z, w2v, acc[r]);
            acc[r] = fmaf(xv.w, w3v, acc[r]);
        }
    }

    const float bb = b1[f];
#pragma unroll
    for (int r = 0; r < 8; ++r) {
        const float v = acc[r] + bb;
        hs[r][f] = 0.5f * v * (1.0f + erff(v * 0.70710678118654752f));
    }
    __syncthreads();

#pragma unroll 1
    for (int o = f; o < 8 * H_; o += 384) {
        const int r = o / H_;
        const int c = o - r * H_;
        float s = 0.0f;
#pragma unroll 4
        for (int k = 0; k < F_; k += 4) {
            const float4 hv = *reinterpret_cast<const float4*>(&hs[r][k]);
            s = fmaf(hv.x, W2[(k + 0) * H_ + c], s);
            s = fmaf(hv.y, W2[(k + 1) * H_ + c], s);
            s = fmaf(hv.z, W2[(k + 2) * H_ + c], s);
            s = fmaf(hv.w, W2[(k + 3) * H_ + c], s);
        }
        g_rw[row0 * H_ + o] = s + b2[c];
    }
}

// ---- K2: max-occupancy combine ---------------------------------------------
// 2048 blocks x 256 threads — 8 blocks/CU = 32 waves/CU (8/SIMD).
// One (b,n) row per block; thread t owns float4 col t. h-loop in batches of 8:
// 8 nontemporal b128 loads in flight per wave (8 KB), x 32 waves = 256 KB/CU.
// ~50 VGPR so full occupancy is register-feasible.
__global__ __launch_bounds__(256) void combine_kernel(
    const float* __restrict__ scores, const float* __restrict__ bias,
    float* __restrict__ out)
{
    const int bn = blockIdx.x;            // 0..2047 (b*1024 + n)
    const int b = bn >> 10;
    const int n = bn & (N_ - 1);
    const int t = threadIdx.x;

    __shared__ float w[H_];
    if (t < H_) w[t] = g_rw[bn * H_ + t];
    __syncthreads();

    const f32x4* __restrict__ sp = reinterpret_cast<const f32x4*>(scores);
    const int base = ((b * H_) * N_ + n) * (M_ / 4) + t;
    const int hstr = N_ * (M_ / 4);       // 262144 float4 per head panel

    f32x4 acc = 0.f;
#pragma unroll 1
    for (int h0 = 0; h0 < H_; h0 += 8) {  // 9 batches of 8
        f32x4 v[8];
#pragma unroll
        for (int u = 0; u < 8; ++u)
            v[u] = __builtin_nontemporal_load(sp + base + (h0 + u) * hstr);
#pragma unroll
        for (int u = 0; u < 8; ++u) {
            const float wh = w[h0 + u];
            acc[0] = fmaf(wh, v[u][0], acc[0]);
            acc[1] = fmaf(wh, v[u][1], acc[1]);
            acc[2] = fmaf(wh, v[u][2], acc[2]);
            acc[3] = fmaf(wh, v[u][3], acc[3]);
        }
    }

    const float bv = bias[0];
#pragma unroll
    for (int j = 0; j < 4; ++j) acc[j] += bv;

    __builtin_nontemporal_store(acc,
        reinterpret_cast<f32x4*>(out) + bn * (M_ / 4) + t);
}

extern "C" void kernel_launch(void* const* d_in, const int* in_sizes, int n_in,
                              void* d_out, int out_size, void* d_ws, size_t ws_size,
                              hipStream_t stream) {
    const float* x      = (const float*)d_in[0];
    const float* scores = (const float*)d_in[1];
    const float* W1     = (const float*)d_in[2];
    const float* b1     = (const float*)d_in[3];
    const float* W2     = (const float*)d_in[4];
    const float* b2     = (const float*)d_in[5];
    const float* bias   = (const float*)d_in[6];
    float* out = (float*)d_out;

    mlp_kernel<<<(B_ * N_) / 8, 384, 0, stream>>>(x, W1, b1, W2, b2);
    combine_kernel<<<B_ * N_, 256, 0, stream>>>(scores, bias, out);
}

// Round 8
// 146.868 us; speedup vs baseline: 1.2462x; 1.2462x over previous
//
#include <hip/hip_runtime.h>
#include <math.h>

// DynamicElementAggregator: B=2, N=1024, M=1024, D=768, F=384, H=72
#define B_ 2
#define N_ 1024
#define M_ 1024
#define D_ 768
#define F_ 384
#define H_ 72

typedef float f32x4 __attribute__((ext_vector_type(4)));

// Raw router weights (2048 x 72, 576 KB). Fully rewritten every call.
__device__ float g_rw[B_ * N_ * H_];

// ---- K1: router MLP (unchanged from Round 5 — known-good) -----------------
__global__ __launch_bounds__(384) void mlp_kernel(
    const float* __restrict__ x, const float* __restrict__ W1,
    const float* __restrict__ b1, const float* __restrict__ W2,
    const float* __restrict__ b2)
{
    const int f = threadIdx.x;            // 0..383
    const int row0 = blockIdx.x * 8;

    __shared__ float xs[8][D_];           // 24 KB
    __shared__ float hs[8][F_ + 8];       // 12.25 KB, pitch 392

    {   // stage x rows (coalesced float4)
        const f32x4* xg = reinterpret_cast<const f32x4*>(x + row0 * D_);
        f32x4* xl = reinterpret_cast<f32x4*>(&xs[0][0]);
#pragma unroll
        for (int i = 0; i < 4; ++i)
            xl[threadIdx.x + i * 384] = xg[threadIdx.x + i * 384];
    }
    __syncthreads();

    float acc[8];
#pragma unroll
    for (int r = 0; r < 8; ++r) acc[r] = 0.0f;

#pragma unroll 4
    for (int d = 0; d < D_; d += 4) {
        const float w0 = W1[(d + 0) * F_ + f];
        const float w1v = W1[(d + 1) * F_ + f];
        const float w2v = W1[(d + 2) * F_ + f];
        const float w3v = W1[(d + 3) * F_ + f];
#pragma unroll
        for (int r = 0; r < 8; ++r) {
            const float4 xv = *reinterpret_cast<const float4*>(&xs[r][d]);
            acc[r] = fmaf(xv.x, w0, acc[r]);
            acc[r] = fmaf(xv.y, w1v, acc[r]);
            acc[r] = fmaf(xv.z, w2v, acc[r]);
            acc[r] = fmaf(xv.w, w3v, acc[r]);
        }
    }

    const float bb = b1[f];
#pragma unroll
    for (int r = 0; r < 8; ++r) {
        const float v = acc[r] + bb;
        hs[r][f] = 0.5f * v * (1.0f + erff(v * 0.70710678118654752f));
    }
    __syncthreads();

#pragma unroll 1
    for (int o = f; o < 8 * H_; o += 384) {
        const int r = o / H_;
        const int c = o - r * H_;
        float s = 0.0f;
#pragma unroll 4
        for (int k = 0; k < F_; k += 4) {
            const float4 hv = *reinterpret_cast<const float4*>(&hs[r][k]);
            s = fmaf(hv.x, W2[(k + 0) * H_ + c], s);
            s = fmaf(hv.y, W2[(k + 1) * H_ + c], s);
            s = fmaf(hv.z, W2[(k + 2) * H_ + c], s);
            s = fmaf(hv.w, W2[(k + 3) * H_ + c], s);
        }
        g_rw[row0 * H_ + o] = s + b2[c];
    }
}

// ---- K2: slab combine, deep-pipelined --------------------------------------
// 512 blocks x 256 threads, 4 rows/block (16 KB contiguous per head — the
// R5-proven granularity). NEW: explicit A/B double-buffered 4-head batches:
// 16 nt loads issued while the previous 16 are consumed -> 16-32 KB in
// flight per wave, 128-256 KB per CU. All reg-array indices compile-time.
__global__ __launch_bounds__(256, 2) void combine_kernel(
    const float* __restrict__ scores, const float* __restrict__ bias,
    float* __restrict__ out)
{
    const int blk = blockIdx.x;           // 0..511
    const int b = blk >> 8;
    const int n0 = (blk & 255) * 4;
    const int t = threadIdx.x;

    __shared__ float w[4 * H_];
    for (int i = t; i < 4 * H_; i += 256)
        w[i] = g_rw[((b << 10) + n0) * H_ + i];
    __syncthreads();

    const f32x4* __restrict__ sp = reinterpret_cast<const f32x4*>(scores);
    const int base = ((b * H_) * N_ + n0) * (M_ / 4) + t;
    const int hstr = N_ * (M_ / 4);       // 262144 float4 per head panel

    f32x4 acc0 = 0.f, acc1 = 0.f, acc2 = 0.f, acc3 = 0.f;
    f32x4 va[16], vb[16];                 // [u*4 + r], all indices static

#define LOAD_BATCH(DST, H0)                                              \
    _Pragma("unroll")                                                    \
    for (int u = 0; u < 4; ++u) {                                        \
        _Pragma("unroll")                                                \
        for (int r = 0; r < 4; ++r)                                      \
            DST[u * 4 + r] = __builtin_nontemporal_load(                 \
                sp + base + ((H0) + u) * hstr + r * 256);                \
    }

#define FMA_BATCH(SRC, H0)                                               \
    _Pragma("unroll")                                                    \
    for (int u = 0; u < 4; ++u) {                                        \
        const float w0 = w[0 * H_ + (H0) + u];                           \
        const float w1 = w[1 * H_ + (H0) + u];                           \
        const float w2 = w[2 * H_ + (H0) + u];                           \
        const float w3 = w[3 * H_ + (H0) + u];                           \
        _Pragma("unroll")                                                \
        for (int j = 0; j < 4; ++j) {                                    \
            acc0[j] = fmaf(w0, SRC[u * 4 + 0][j], acc0[j]);              \
            acc1[j] = fmaf(w1, SRC[u * 4 + 1][j], acc1[j]);              \
            acc2[j] = fmaf(w2, SRC[u * 4 + 2][j], acc2[j]);              \
            acc3[j] = fmaf(w3, SRC[u * 4 + 3][j], acc3[j]);              \
        }                                                                \
    }

    LOAD_BATCH(va, 0)                     // prologue: h 0..3
#pragma unroll 1
    for (int i = 0; i < 9; ++i) {         // h0 = 8*i; 9*8 = 72 heads
        const int h0 = i * 8;
        LOAD_BATCH(vb, h0 + 4)            // issue h0+4..h0+7
        FMA_BATCH(va, h0)                 // consume h0..h0+3
        if (i < 8) { LOAD_BATCH(va, h0 + 8) }  // issue next iter's A
        FMA_BATCH(vb, h0 + 4)             // consume h0+4..h0+7
    }
#undef LOAD_BATCH
#undef FMA_BATCH

    const float bv = bias[0];
#pragma unroll
    for (int j = 0; j < 4; ++j) {
        acc0[j] += bv; acc1[j] += bv; acc2[j] += bv; acc3[j] += bv;
    }

    f32x4* __restrict__ op = reinterpret_cast<f32x4*>(out);
    const int obase = ((b << 10) + n0) * (M_ / 4) + t;
    __builtin_nontemporal_store(acc0, op + obase);
    __builtin_nontemporal_store(acc1, op + obase + 256);
    __builtin_nontemporal_store(acc2, op + obase + 512);
    __builtin_nontemporal_store(acc3, op + obase + 768);
}

extern "C" void kernel_launch(void* const* d_in, const int* in_sizes, int n_in,
                              void* d_out, int out_size, void* d_ws, size_t ws_size,
                              hipStream_t stream) {
    const float* x      = (const float*)d_in[0];
    const float* scores = (const float*)d_in[1];
    const float* W1     = (const float*)d_in[2];
    const float* b1     = (const float*)d_in[3];
    const float* W2     = (const float*)d_in[4];
    const float* b2     = (const float*)d_in[5];
    const float* bias   = (const float*)d_in[6];
    float* out = (float*)d_out;

    mlp_kernel<<<(B_ * N_) / 8, 384, 0, stream>>>(x, W1, b1, W2, b2);
    combine_kernel<<<(B_ * N_) / 4, 256, 0, stream>>>(scores, bias, out);
}